// Round 5
// baseline (96.218 us; speedup 1.0000x reference)
//
#include <hip/hip_runtime.h>

// QuantumAttention: B=8, S=2048, E=8, H=2, D=4, NQ=8
//
// Cross-round accounting (R5..R9 reconcile only this way): total =
// fill 40.5 + attn + merge + ~18us graph-node overhead (3 nodes, ~6/node).
// attn6/9 ~= 26us, quantum/merge ~2-3us. Earlier "quantum=21.5" inference
// was node-overhead misattributed; R9's merge rebuild was neutral for that
// reason. Bottleneck: attn LDS pipe. Broadcast ds_read_b128 count =
// 2*pairs/(64*M) -> at M=2: 49K cyc/CU ~= 20.5us (VALU floor only 8.5us).
// R10: M=4 rows/lane (LDS -> 10.2us), 16 j-windows of 128, 32-j wave
// slices, 2048 blocks x 4 waves, VGPR target <=64 for 8 waves/SIMD.
// kv4 LDS aliased with reduce scratch (extra barrier) -> 15.7KB/block,
// 8 blocks/CU. Merge: 16 slices now (mechanical).
//
// Quantum circuit closed-form: c_w = cos(tok[w]+tok[w%4]);
// z[0]=c1..c7, z[q>=1]=c0..cq. Softmax one-pass (scores bounded, fp32 safe);
// 0.5*log2(e) folded into Wq so inner exp is bare v_exp_f32 (exp2).

#define SS 2048
#define EE 8

// grid 2048: bid = b<<8 | h<<7 | rt<<4 | jw.  256 threads = 4 waves.
// Block: rows rt*256..+255 (4/lane, stride 64), j-window jw*128..+127
// (32 j per wave). All 4 waves share the same 256 rows.
extern "C" __global__ __launch_bounds__(256, 8)
void qa_attn10(const float* __restrict__ x, const float* __restrict__ Wq,
               const float* __restrict__ Wk, const float* __restrict__ Wv,
               float* __restrict__ wsD, float4* __restrict__ wsA) {
    __shared__ float wrow[96];                      // wq'(scaled), wk, wv
    __shared__ __align__(16) unsigned char smem[15360];
    float4* kv4  = (float4*)smem;                   // 128 j x {K4,V4} = 4KB
    float*  rden = (float*)smem;                    // ALIAS (after barrier): 3KB
    float4* racc = (float4*)(smem + 3072);          // 12KB

    const int bid = blockIdx.x;
    const int jw = bid & 15, rt = (bid >> 4) & 7, h = (bid >> 7) & 1, b = bid >> 8;
    const int tid = threadIdx.x, lane = tid & 63, w = tid >> 6;

    if (tid < 96) {
        const int grp = tid >> 5, d = (tid >> 3) & 3, e = tid & 7;
        const float* W = (grp == 0) ? Wq : (grp == 1 ? Wk : Wv);
        float val = W[(h * 4 + d) * EE + e];
        if (grp == 0) val *= 0.72134752044f;   // 0.5 * log2(e)
        wrow[tid] = val;
    }
    __syncthreads();   // wrow ready

    // ---- stage K,V for the 128-j window (two threads per j: K half / V half)
    {
        const int jloc = tid >> 1, half = tid & 1;
        const int j = jw * 128 + jloc;
        const float* xp = x + ((size_t)(b * SS + j)) * EE;
        float xv[8];
        *(float4*)&xv[0] = *(const float4*)xp;
        *(float4*)&xv[4] = *(const float4*)(xp + 4);
        const float* wsel = wrow + 32 + half * 32;   // wk | wv
        float o[4];
        #pragma unroll
        for (int d = 0; d < 4; ++d) {
            float s = 0.f;
            #pragma unroll
            for (int e = 0; e < 8; ++e) s += xv[e] * wsel[d * 8 + e];
            o[d] = s;
        }
        kv4[jloc * 2 + half] = make_float4(o[0], o[1], o[2], o[3]);
    }

    // ---- q' (log2-scaled) for this lane's 4 rows (stride 64) ----
    float q[4][4];
    const int row0 = rt * 256 + lane;
    #pragma unroll
    for (int m = 0; m < 4; ++m) {
        const float* xp = x + ((size_t)(b * SS + row0 + m * 64)) * EE;
        float xv[8];
        *(float4*)&xv[0] = *(const float4*)xp;
        *(float4*)&xv[4] = *(const float4*)(xp + 4);
        #pragma unroll
        for (int d = 0; d < 4; ++d) {
            float s = 0.f;
            #pragma unroll
            for (int e = 0; e < 8; ++e) s += xv[e] * wrow[d * 8 + e];
            q[m][d] = s;
        }
    }
    __syncthreads();   // kv4 ready

    // ---- 32-j slice for this wave, 4 rows per lane ----
    float den[4] = {};
    float acc[4][4] = {};
    const float4* kvp = &kv4[w * 64];   // w*32 j, 2 float4 each
    #pragma unroll 2
    for (int jl = 0; jl < 32; ++jl) {
        const float4 kk = kvp[jl * 2];      // wave-broadcast
        const float4 vv = kvp[jl * 2 + 1];
        #pragma unroll
        for (int m = 0; m < 4; ++m) {
            const float s = q[m][0] * kk.x + q[m][1] * kk.y
                          + q[m][2] * kk.z + q[m][3] * kk.w;
            const float e = __builtin_amdgcn_exp2f(s);
            den[m] += e;
            acc[m][0] += e * vv.x; acc[m][1] += e * vv.y;
            acc[m][2] += e * vv.z; acc[m][3] += e * vv.w;
        }
    }
    __syncthreads();   // kv4 dead; smem becomes reduce scratch

    // ---- single-stage reduce: waves 1..3 park, wave 0 merges + writes ----
    if (w > 0) {
        #pragma unroll
        for (int m = 0; m < 4; ++m) {
            rden[(w - 1) * 256 + lane + m * 64] = den[m];
            racc[(w - 1) * 256 + lane + m * 64] =
                make_float4(acc[m][0], acc[m][1], acc[m][2], acc[m][3]);
        }
    }
    __syncthreads();
    if (w == 0) {
        #pragma unroll
        for (int m = 0; m < 4; ++m) {
            const int r = lane + m * 64;
            float d = den[m] + rden[r] + rden[256 + r] + rden[512 + r];
            float4 a1 = racc[r], a2 = racc[256 + r], a3 = racc[512 + r];
            float4 a = make_float4(acc[m][0] + a1.x + a2.x + a3.x,
                                   acc[m][1] + a1.y + a2.y + a3.y,
                                   acc[m][2] + a1.z + a2.z + a3.z,
                                   acc[m][3] + a1.w + a2.w + a3.w);
            const size_t idx = ((size_t)((b * 2 + h) * 16 + jw)) * SS + row0 + m * 64;
            wsD[idx] = d;
            wsA[idx] = a;
        }
    }
}

// ---- merge + quantum: 2 threads/token (one per head), shfl_xor exchange.
// 128 blocks x 256 threads; now 16 slices per (token, head).
extern "C" __global__ __launch_bounds__(256)
void qa_merge10(const float* __restrict__ wsD, const float4* __restrict__ wsA,
                const float* __restrict__ Wo, float* __restrict__ out) {
    __shared__ float wo[64];
    const int tid = threadIdx.x;
    if (tid < 64) wo[tid] = Wo[tid];
    __syncthreads();

    const int gt = blockIdx.x * 256 + tid;   // 0..32767
    const int g = gt >> 1, h = gt & 1;       // token, head
    const int b = g >> 11, s = g & 2047;

    float den = 0.f, a0 = 0.f, a1 = 0.f, a2 = 0.f, a3 = 0.f;
    #pragma unroll
    for (int sl = 0; sl < 16; ++sl) {
        const size_t idx = ((size_t)((b * 2 + h) * 16 + sl)) * SS + s;
        den += wsD[idx];
        const float4 p = wsA[idx];
        a0 += p.x; a1 += p.y; a2 += p.z; a3 += p.w;
    }
    const float inv = 1.f / den;
    float own[4] = {a0 * inv, a1 * inv, a2 * inv, a3 * inv};
    float oth[4];
    #pragma unroll
    for (int c = 0; c < 4; ++c) oth[c] = __shfl_xor(own[c], 1);

    float tok[8];
    #pragma unroll
    for (int c = 0; c < 4; ++c) {
        tok[c]     = h ? oth[c] : own[c];
        tok[4 + c] = h ? own[c] : oth[c];
    }

    float cc[8];
    #pragma unroll
    for (int ww = 0; ww < 8; ++ww) cc[ww] = __cosf(tok[ww] + tok[ww & 3]);

    float z[8];
    float p = 1.f;
    #pragma unroll
    for (int qq = 1; qq < 8; ++qq) { p *= cc[qq]; z[qq] = p; }
    z[0] = p;                       // c1..c7
    #pragma unroll
    for (int qq = 1; qq < 8; ++qq) z[qq] *= cc[0];   // c0..cq

    // this thread writes outputs f = h*4 .. h*4+3
    float y[4];
    #pragma unroll
    for (int f = 0; f < 4; ++f) {
        float sum = 0.f;
        #pragma unroll
        for (int qq = 0; qq < 8; ++qq) sum += z[qq] * wo[(h * 4 + f) * 8 + qq];
        y[f] = sum;
    }
    float4* op = (float4*)(out + (size_t)g * 8) + h;
    *op = make_float4(y[0], y[1], y[2], y[3]);
}

extern "C" void kernel_launch(void* const* d_in, const int* in_sizes, int n_in,
                              void* d_out, int out_size, void* d_ws, size_t ws_size,
                              hipStream_t stream) {
    const float* x  = (const float*)d_in[0];
    const float* Wq = (const float*)d_in[1];
    const float* Wk = (const float*)d_in[2];
    const float* Wv = (const float*)d_in[3];
    const float* Wo = (const float*)d_in[4];
    float* out = (float*)d_out;

    float*  wsD = (float*)d_ws;                          // 16*16*2048 floats = 2 MB
    float4* wsA = (float4*)((char*)d_ws + (16 * 16 * 2048) * sizeof(float)); // 8 MB

    qa_attn10<<<dim3(2048), dim3(256), 0, stream>>>(x, Wq, Wk, Wv, wsD, wsA);
    qa_merge10<<<dim3(128), dim3(256), 0, stream>>>(wsD, wsA, Wo, out);
}